// Round 12
// baseline (1307.122 us; speedup 1.0000x reference)
//
#include <hip/hip_runtime.h>

// VisionMamba: B=2, L=1024 (16x8x8), d=384, 12 layers, dstate=16, dconv=4, dtrank=24
// R12: (a) keep R11 patch (41us, coalesced linear stage); (b) LN fused into
// in_proj GEMM at 32-ROW tiles (R7 failed at 64-row: 50KB LDS capped occupancy;
// now 24.5KB -> 6 blocks/CU, LN prologue 8thr/row) - removes 12 dispatches;
// (c) gemm1 reverted to R10 (32,6,2) 64-row shape (R11 32-row split cost ~+6us).
// Proven: patch z=4 4-plane coalesced, LDS-staged scans, convfused.

#define NTOK 2048

typedef short bf16x8 __attribute__((ext_vector_type(8)));
typedef float f32x4 __attribute__((ext_vector_type(4)));
typedef unsigned short us4 __attribute__((ext_vector_type(4)));

__device__ __forceinline__ float bf2f(unsigned short u) {
    return __uint_as_float(((unsigned)u) << 16);
}
__device__ __forceinline__ unsigned short f2bf(float f) {
    unsigned u = __float_as_uint(f);
    u += 0x7fffu + ((u >> 16) & 1u);
    return (unsigned short)(u >> 16);
}
__device__ __forceinline__ float siluf(float x) { return x / (1.f + expf(-x)); }

__device__ __forceinline__ float ldr(const void* p, size_t i, int bf) {
    if (bf) return bf2f(((const unsigned short*)p)[i]);
    return ((const float*)p)[i];
}
template<int BF>
__device__ __forceinline__ float ld(const void* p, size_t i) {
    if (BF) return bf2f(((const unsigned short*)p)[i]);
    return ((const float*)p)[i];
}

__global__ void detect_kernel(const void* dskip, int* flag) {
    flag[0] = (((const unsigned short*)dskip)[0] == 0x3F80u) ? 1 : 0;
}

// ---------------- patch_w transpose: [4096][384] -> wtP[384][4096] bf16 ----------------
__global__ __launch_bounds__(256)
void transposeP_kernel(const int* flag, const void* pw, unsigned short* wtP)
{
    __shared__ unsigned short Ts[32 * 36];
    const int bid = blockIdx.x;           // 1536 = 128 kb x 12 nb
    const int kb = bid / 12, nb = bid % 12;
    const int tid = threadIdx.x;
    const int r = tid >> 3, c0 = (tid & 7) * 4;
    const int BF = *flag;
#pragma unroll
    for (int i = 0; i < 4; i++) {
        size_t si = (size_t)(kb * 32 + r) * 384 + nb * 32 + c0 + i;
        Ts[(c0 + i) * 36 + r] = f2bf(ldr(pw, si, BF));
    }
    __syncthreads();
    *(us4*)(wtP + (size_t)(nb * 32 + r) * 4096 + kb * 32 + c0) = *(const us4*)&Ts[r * 36 + c0];
}

// ---------- per-layer transpose (small-ws fallback): in_proj->wtL, out_proj->wtO ----------
__global__ __launch_bounds__(256)
void transposeL_kernel(const int* flag, const void* ipw, const void* opw, int lyr,
                       unsigned short* wtL, unsigned short* wtOl)
{
    __shared__ unsigned short Ts[32 * 36];
    const int bid = blockIdx.x;           // 432 = 288 (in_proj 12kb x 24nb) + 144 (12x12)
    const void* src; size_t soff; unsigned short* dst; int N, kb, nb;
    if (bid < 288) {
        src = ipw; soff = (size_t)lyr * 294912; dst = wtL; N = 768;
        kb = bid / 24; nb = bid % 24;
    } else {
        int rel = bid - 288;
        src = opw; soff = (size_t)lyr * 147456; dst = wtOl; N = 384;
        kb = rel / 12; nb = rel % 12;
    }
    const int tid = threadIdx.x;
    const int r = tid >> 3, c0 = (tid & 7) * 4;
    const int BF = *flag;
#pragma unroll
    for (int i = 0; i < 4; i++) {
        size_t si = soff + (size_t)(kb * 32 + r) * N + nb * 32 + c0 + i;
        Ts[(c0 + i) * 36 + r] = f2bf(ldr(src, si, BF));
    }
    __syncthreads();
    *(us4*)(dst + (size_t)(nb * 32 + r) * 384 + kb * 32 + c0) = *(const us4*)&Ts[r * 36 + c0];
}

// ---------- all-layer transpose (big-ws mode): one dispatch for 12 layers ----------
__global__ __launch_bounds__(256)
void transposeAll_kernel(const int* flag, const void* ipw, const void* opw,
                         unsigned short* wtL12, unsigned short* wtO12)
{
    __shared__ unsigned short Ts[32 * 36];
    const int lyr = blockIdx.y;
    const int bid = blockIdx.x;           // 432 per layer
    const void* src; size_t soff; unsigned short* dst; int N, kb, nb;
    if (bid < 288) {
        src = ipw; soff = (size_t)lyr * 294912;
        dst = wtL12 + (size_t)lyr * 294912; N = 768;
        kb = bid / 24; nb = bid % 24;
    } else {
        int rel = bid - 288;
        src = opw; soff = (size_t)lyr * 147456;
        dst = wtO12 + (size_t)lyr * 147456; N = 384;
        kb = rel / 12; nb = rel % 12;
    }
    const int tid = threadIdx.x;
    const int r = tid >> 3, c0 = (tid & 7) * 4;
    const int BF = *flag;
#pragma unroll
    for (int i = 0; i < 4; i++) {
        size_t si = soff + (size_t)(kb * 32 + r) * N + nb * 32 + c0 + i;
        Ts[(c0 + i) * 36 + r] = f2bf(ldr(src, si, BF));
    }
    __syncthreads();
    *(us4*)(dst + (size_t)(nb * 32 + r) * 384 + kb * 32 + c0) = *(const us4*)&Ts[r * 36 + c0];
}

// ================= out_proj GEMM (R10 shape): 64m x 64n, 4 waves 2x2, z=2 K-split =================
__global__ __launch_bounds__(256)
void gemm1_kernel(const unsigned short* __restrict__ A,
                  const unsigned short* __restrict__ WT,
                  float* __restrict__ out0)
{
    const int mtile = blockIdx.x;
    const int ntile = blockIdx.y;
    const int tid = threadIdx.x;
    const int w = tid >> 6, lane = tid & 63;
    const int l15 = lane & 15, quad = lane >> 4;
    const int mbase = mtile * 64 + (w & 1) * 32;
    const int nbase = ntile * 64 + (w >> 1) * 32;
    f32x4 acc00 = {0.f,0.f,0.f,0.f}, acc01 = acc00, acc10 = acc00, acc11 = acc00;
    const bf16x8* Ap0 = (const bf16x8*)(A + (size_t)(mbase + l15) * 384 + quad * 8);
    const bf16x8* Ap1 = (const bf16x8*)(A + (size_t)(mbase + 16 + l15) * 384 + quad * 8);
    const bf16x8* Bp0 = (const bf16x8*)(WT + (size_t)(nbase + l15) * 384 + quad * 8);
    const bf16x8* Bp1 = (const bf16x8*)(WT + (size_t)(nbase + 16 + l15) * 384 + quad * 8);
    const int kt0 = blockIdx.z * 6;
#pragma unroll
    for (int ki = 0; ki < 6; ki++) {
        const int kt = kt0 + ki;
        bf16x8 a0 = Ap0[kt * 4];
        bf16x8 a1 = Ap1[kt * 4];
        bf16x8 b0 = Bp0[kt * 4];
        bf16x8 b1 = Bp1[kt * 4];
        acc00 = __builtin_amdgcn_mfma_f32_16x16x32_bf16(a0, b0, acc00, 0, 0, 0);
        acc01 = __builtin_amdgcn_mfma_f32_16x16x32_bf16(a0, b1, acc01, 0, 0, 0);
        acc10 = __builtin_amdgcn_mfma_f32_16x16x32_bf16(a1, b0, acc10, 0, 0, 0);
        acc11 = __builtin_amdgcn_mfma_f32_16x16x32_bf16(a1, b1, acc11, 0, 0, 0);
    }
    f32x4 accs[2][2] = {{acc00, acc01}, {acc10, acc11}};
#pragma unroll
    for (int mi = 0; mi < 2; mi++)
#pragma unroll
    for (int ni = 0; ni < 2; ni++)
#pragma unroll
    for (int r = 0; r < 4; r++) {
        int m = mbase + mi * 16 + quad * 4 + r;
        int n = nbase + ni * 16 + l15;
        atomicAdd(&out0[(size_t)m * 384 + n], accs[mi][ni][r]);
    }
}

// ---------- fused layernorm + in_proj GEMM (32-row tiles): LN into 24.5KB LDS, then MFMA ----------
// grid (64, 12); block 256. LN: row = tid>>3 (0..31), 8 threads/row x 48 f32.
// As[32][392] bf16 (24.5KB -> 6 blocks/CU). MFMA: wave w -> n = ntile*64 + w*16, 2 accs.
__global__ __launch_bounds__(256)
void lngemm_kernel(const int* flag, const float* __restrict__ tok,
                   const void* __restrict__ nw, const void* __restrict__ nb, int woff,
                   const unsigned short* __restrict__ WT,
                   unsigned short* __restrict__ xi, unsigned short* __restrict__ zs)
{
    __shared__ short As[32 * 392];
    const int BF = *flag;
    const int mtile = blockIdx.x;
    const int ntile = blockIdx.y;
    const int tid = threadIdx.x;
    const int w = tid >> 6, lane = tid & 63;
    const int l15 = lane & 15, quad = lane >> 4;
    // ---- LN prologue ----
    {
        const int row = tid >> 3, oct = tid & 7;
        const float* src = tok + (size_t)(mtile * 32 + row) * 384 + oct * 48;
        float4 v[12];
        float s = 0.f, s2 = 0.f;
#pragma unroll
        for (int j = 0; j < 12; j++) {
            v[j] = ((const float4*)src)[j];
            s  += v[j].x + v[j].y + v[j].z + v[j].w;
            s2 += v[j].x * v[j].x + v[j].y * v[j].y + v[j].z * v[j].z + v[j].w * v[j].w;
        }
        s  += __shfl_xor(s, 1);  s  += __shfl_xor(s, 2);  s  += __shfl_xor(s, 4);
        s2 += __shfl_xor(s2, 1); s2 += __shfl_xor(s2, 2); s2 += __shfl_xor(s2, 4);
        const float mu = s * (1.f / 384.f);
        const float rstd = rsqrtf(fmaxf(s2 * (1.f / 384.f) - mu * mu, 0.f) + 1e-5f);
        short* dst = As + row * 392 + oct * 48;
#pragma unroll
        for (int j = 0; j < 12; j++) {
            int c = woff + oct * 48 + j * 4;
            us4 o;
            o[0] = f2bf((v[j].x - mu) * rstd * ldr(nw, c + 0, BF) + ldr(nb, c + 0, BF));
            o[1] = f2bf((v[j].y - mu) * rstd * ldr(nw, c + 1, BF) + ldr(nb, c + 1, BF));
            o[2] = f2bf((v[j].z - mu) * rstd * ldr(nw, c + 2, BF) + ldr(nb, c + 2, BF));
            o[3] = f2bf((v[j].w - mu) * rstd * ldr(nw, c + 3, BF) + ldr(nb, c + 3, BF));
            *(us4*)(dst + j * 4) = o;
        }
    }
    __syncthreads();
    // ---- MFMA: 32m x 64n; A from LDS, B global ----
    const int nbase = ntile * 64 + w * 16;
    f32x4 acc0 = {0.f,0.f,0.f,0.f}, acc1 = acc0;
    const bf16x8* Bp = (const bf16x8*)(WT + (size_t)(nbase + l15) * 384 + quad * 8);
#pragma unroll
    for (int kt = 0; kt < 12; kt++) {
        const short* a0p = As + l15 * 392 + kt * 32 + quad * 8;
        const short* a1p = a0p + 16 * 392;
        bf16x8 a0, a1;
        {
            us4 lo = *(const us4*)a0p, hi = *(const us4*)(a0p + 4);
            a0[0]=lo[0]; a0[1]=lo[1]; a0[2]=lo[2]; a0[3]=lo[3];
            a0[4]=hi[0]; a0[5]=hi[1]; a0[6]=hi[2]; a0[7]=hi[3];
            us4 lo1 = *(const us4*)a1p, hi1 = *(const us4*)(a1p + 4);
            a1[0]=lo1[0]; a1[1]=lo1[1]; a1[2]=lo1[2]; a1[3]=lo1[3];
            a1[4]=hi1[0]; a1[5]=hi1[1]; a1[6]=hi1[2]; a1[7]=hi1[3];
        }
        bf16x8 b = Bp[kt * 4];
        acc0 = __builtin_amdgcn_mfma_f32_16x16x32_bf16(a0, b, acc0, 0, 0, 0);
        acc1 = __builtin_amdgcn_mfma_f32_16x16x32_bf16(a1, b, acc1, 0, 0, 0);
    }
    f32x4 accs[2] = {acc0, acc1};
#pragma unroll
    for (int mi = 0; mi < 2; mi++)
#pragma unroll
    for (int r = 0; r < 4; r++) {
        int m = mtile * 32 + mi * 16 + quad * 4 + r;
        int n = nbase + l15;
        float v = accs[mi][r];
        if (n < 384) xi[(size_t)m * 384 + n] = f2bf(v);
        else zs[(size_t)m * 384 + (n - 384)] = f2bf(siluf(v));
    }
}

// ---------------- pos-embed + patch_b init of tok ----------------
template<int BF>
__device__ void posinit_body(const void* __restrict__ pb, const void* __restrict__ bparams,
                             const unsigned char* __restrict__ maskp, float* __restrict__ tok)
{
    const int gid = blockIdx.x * 256 + threadIdx.x;   // 786432 total
    const int t = gid / 384;
    const int n = gid - t * 384;
    const int b = t >> 10, l = t & 1023;
    const int gh = l >> 6, gw = (l >> 3) & 7, gd = l & 7;
    const int j = n >> 7;
    const int ii = n & 127;
    const int i0 = (ii < 64) ? ii : ii - 64;
    const float omega = exp2f(-(float)i0 * 0.20762050593046014f);  // 10000^(-i/64)
    float rr = ld<BF>(bparams, b * 4 + 0);
    float ar = ld<BF>(bparams, b * 4 + 1);
    float vr = ld<BF>(bparams, b * 4 + 2);
    bool mk = maskp[b] != 0;
    float cj;
    if (j == 0) {
        float dmax = (rr >= 0.f) ? 15.f * rr : 0.f;
        if (dmax == 0.f) dmax = 1.f;
        cj = (float)gh * rr / dmax;
    } else if (j == 1) {
        float amax = 4.f * fabsf(ar);
        if (amax == 0.f) amax = 1.f;
        cj = (float)(gw - 4) * ar / amax;
    } else {
        if (mk) {
            float dmx = 4.f * fabsf(vr);
            if (dmx == 0.f) dmx = 1.f;
            cj = (float)(gd - 4) * vr / dmx;
        } else {
            float dmx = (vr >= 0.f) ? 7.f * vr : 0.f;
            if (dmx == 0.f) dmx = 1.f;
            cj = (float)gd * vr / dmx;
        }
    }
    float s = cj * omega;
    float pos = (ii < 64) ? sinf(s) : cosf(s);
    tok[gid] = ld<BF>(pb, n) + pos;
}

__global__ __launch_bounds__(256)
void posinit_kernel(const int* flag, const void* pb, const void* bparams,
                    const unsigned char* maskp, float* tok)
{
    if (*flag) posinit_body<1>(pb, bparams, maskp, tok);
    else       posinit_body<0>(pb, bparams, maskp, tok);
}

// patch MFMA with LDS-staged A: block = 64 tok x 64 n; kz covers 4 ph planes (z=4).
// Coalesced linear stage (R11): decode (gw,pw,gd,pd) from e, write As[(gw*8+gd)*260+pw*8+pd].
template<int BF>
__device__ void patch_body(const void* __restrict__ x,
                           const unsigned short* __restrict__ WT,
                           float* __restrict__ tok, short* __restrict__ As)
{
    const int mtile = blockIdx.x;   // 32  (fixed b = mtile>>4, gh = mtile&15)
    const int ntile = blockIdx.y;   // 6
    const int kz = blockIdx.z;      // 4 (each = 4 ph planes)
    const int tid = threadIdx.x;
    const int w = tid >> 6, lane = tid & 63;
    const int l15 = lane & 15, quad = lane >> 4;
    const int nbase = ntile * 64 + (w >> 1) * 32;
    const int mrow0 = (w & 1) * 32 + l15;
    const int bb0 = mtile >> 4, gh0 = mtile & 15;
    f32x4 acc00 = {0.f,0.f,0.f,0.f}, acc01 = acc00, acc10 = acc00, acc11 = acc00;
#pragma unroll
    for (int p2 = 0; p2 < 4; p2++) {
        const int plane = kz * 4 + p2;
        if (p2) __syncthreads();     // all waves done reading As before restage
        {
            const size_t sbase = (size_t)bb0 * 4194304u + (size_t)gh0 * 262144u
                               + (size_t)plane * 16384u;
#pragma unroll
            for (int it = 0; it < 16; it++) {
                int e = it * 1024 + tid * 4;
                int gw = e >> 11, pw = (e >> 6) & 31, gd = (e >> 3) & 7, pd = e & 7;
                short* dst = As + (gw * 8 + gd) * 260 + pw * 8 + pd;
                if (BF) {
                    *(us4*)dst = *(const us4*)((const unsigned short*)x + sbase + e);
                } else {
                    float4 p4 = *(const float4*)((const float*)x + sbase + e);
                    dst[0] = (short)f2bf(p4.x); dst[1] = (short)f2bf(p4.y);
                    dst[2] = (short)f2bf(p4.z); dst[3] = (short)f2bf(p4.w);
                }
            }
        }
        __syncthreads();
        const bf16x8* Bp0 = (const bf16x8*)(WT + (size_t)(nbase + l15) * 4096
                                            + plane * 256 + quad * 8);
        const bf16x8* Bp1 = (const bf16x8*)(WT + (size_t)(nbase + 16 + l15) * 4096
                                            + plane * 256 + quad * 8);
#pragma unroll
        for (int kt = 0; kt < 8; kt++) {
            const short* a0p = As + mrow0 * 260 + kt * 32 + quad * 8;
            const short* a1p = a0p + 16 * 260;
            bf16x8 a0, a1;
            {
                us4 lo = *(const us4*)a0p, hi = *(const us4*)(a0p + 4);
                a0[0]=lo[0]; a0[1]=lo[1]; a0[2]=lo[2]; a0[3]=lo[3];
                a0[4]=hi[0]; a0[5]=hi[1]; a0[6]=hi[2]; a0[7]=hi[3];
                us4 lo1 = *(const us4*)a1p, hi1 = *(const us4*)(a1p + 4);
                a1[0]=lo1[0]; a1[1]=lo1[1]; a1[2]=lo1[2]; a1[3]=lo1[3];
                a1[4]=hi1[0]; a1[5]=hi1[1]; a1[6]=hi1[2]; a1[7]=hi1[3];
            }
            bf16x8 b0 = Bp0[kt * 4];
            bf16x8 b1 = Bp1[kt * 4];
            acc00 = __builtin_amdgcn_mfma_f32_16x16x32_bf16(a0, b0, acc00, 0, 0, 0);
            acc01 = __builtin_amdgcn_mfma_f32_16x16x32_bf16(a0, b1, acc01, 0, 0, 0);
            acc10 = __builtin_amdgcn_mfma_f32_16x16x32_bf16(a1, b0, acc10, 0, 0, 0);
            acc11 = __builtin_amdgcn_mfma_f32_16x16x32_bf16(a1, b1, acc11, 0, 0, 0);
        }
    }
    f32x4 accs[2][2] = {{acc00, acc01}, {acc10, acc11}};
#pragma unroll
    for (int mi = 0; mi < 2; mi++)
#pragma unroll
    for (int ni = 0; ni < 2; ni++) {
        int n = nbase + ni * 16 + l15;
#pragma unroll
        for (int r = 0; r < 4; r++) {
            int m = mtile * 64 + (w & 1) * 32 + mi * 16 + quad * 4 + r;
            atomicAdd(&tok[(size_t)m * 384 + n], accs[mi][ni][r]);
        }
    }
}

__global__ __launch_bounds__(256)
void patch_kernel(const int* flag, const void* x, const unsigned short* wtP, float* tok)
{
    __shared__ short As[64 * 260];   // 33.3 KB
    if (*flag) patch_body<1>(x, wtP, tok, As);
    else       patch_body<0>(x, wtP, tok, As);
}

// ---------------- layernorm (final): one wave per token; in tok f32 ----------------
__global__ __launch_bounds__(64)
void ln_kernel(const int* flag, const float* __restrict__ in, const void* __restrict__ w,
               const void* __restrict__ b, int woff, void* __restrict__ out, int obf)
{
    const int BF = *flag;
    const int wbf = obf | BF;
    const int t = blockIdx.x;
    const int lane = threadIdx.x;
    float v[6];
    float s = 0.f;
#pragma unroll
    for (int i = 0; i < 6; i++) { v[i] = in[(size_t)t * 384 + lane + 64 * i]; s += v[i]; }
#pragma unroll
    for (int o = 1; o < 64; o <<= 1) s += __shfl_xor(s, o);
    const float mu = s * (1.f / 384.f);
    float s2 = 0.f;
#pragma unroll
    for (int i = 0; i < 6; i++) { float d = v[i] - mu; s2 += d * d; }
#pragma unroll
    for (int o = 1; o < 64; o <<= 1) s2 += __shfl_xor(s2, o);
    const float rstd = rsqrtf(s2 * (1.f / 384.f) + 1e-5f);
#pragma unroll
    for (int i = 0; i < 6; i++) {
        int c = lane + 64 * i;
        float o = (v[i] - mu) * rstd * ldr(w, woff + c, BF) + ldr(b, woff + c, BF);
        if (wbf) ((unsigned short*)out)[(size_t)t * 384 + c] = f2bf(o);
        else     ((float*)out)[(size_t)t * 384 + c] = o;
    }
}

// ------- fused: causal depthwise conv(4)+silu -> x_proj (384->56) -> dt_proj (24->384) -------
template<int BF>
__device__ void convfused_body(float* xcs, float* dblA,
                          const unsigned short* __restrict__ xi,
                          const void* __restrict__ cw, const void* __restrict__ cb,
                          const void* __restrict__ xpw, const void* __restrict__ dtw,
                          const void* __restrict__ dtbp, int lyr,
                          unsigned short* __restrict__ xc, unsigned short* __restrict__ dtv,
                          float* __restrict__ Bm, float* __restrict__ Cm)
{
    const int tb = blockIdx.x * 4;
    const int tid = threadIdx.x;
    const size_t cwo = (size_t)lyr * 1536;
    const size_t cbo = (size_t)lyr * 384;
    const size_t xpo = (size_t)lyr * 21504;
    const size_t dto = (size_t)lyr * 9216;
#pragma unroll
    for (int i = 0; i < 6; i++) {
        int p = i * 256 + tid;
        int tl = p / 384, c = p - tl * 384;
        int t = tb + tl;
        int b = t >> 10, l = t & 1023;
        float acc = ld<BF>(cb, cbo + c);
#pragma unroll
        for (int jj = 0; jj < 4; jj++) {
            int ls = l - 3 + jj;
            if (ls >= 0)
                acc = fmaf(bf2f(xi[(size_t)((b << 10) + ls) * 384 + c]),
                           ld<BF>(cw, cwo + c * 4 + jj), acc);
        }
        float s = siluf(acc);
        xcs[tl * 384 + c] = s;
        xc[(size_t)t * 384 + c] = f2bf(s);
    }
    __syncthreads();
    {
        const int tok = tid >> 6, og = tid & 63;
        const int t = tb + tok;
        if (og < 56) {
            float acc = 0.f;
            const float* xr = xcs + tok * 384;
#pragma unroll 8
            for (int k = 0; k < 384; k++)
                acc = fmaf(xr[k], ld<BF>(xpw, xpo + (size_t)k * 56 + og), acc);
            if (og < 24) dblA[tok * 24 + og] = acc;
            else if (og < 40) Bm[(size_t)t * 16 + (og - 24)] = acc;
            else Cm[(size_t)t * 16 + (og - 40)] = acc;
        }
    }
    __syncthreads();
#pragma unroll
    for (int i = 0; i < 6; i++) {
        int p = i * 256 + tid;
        int tl = p / 384, c = p - tl * 384;
        int t = tb + tl;
        float acc = ld<BF>(dtbp, cbo + c);
        const float* dr = dblA + tl * 24;
#pragma unroll
        for (int r = 0; r < 24; r++)
            acc = fmaf(dr[r], ld<BF>(dtw, dto + (size_t)r * 384 + c), acc);
        float sp = fmaxf(acc, 0.f) + log1pf(expf(-fabsf(acc)));  // softplus
        dtv[(size_t)t * 384 + c] = f2bf(sp);
    }
}

__global__ __launch_bounds__(256)
void convfused_kernel(const int* flag, const unsigned short* xi, const void* cw,
                      const void* cb, const void* xpw, const void* dtw, const void* dtbp,
                      int lyr, unsigned short* xc, unsigned short* dtv,
                      float* Bm, float* Cm)
{
    __shared__ float xcs[4 * 384];
    __shared__ float dblA[4 * 24];
    if (*flag) convfused_body<1>(xcs, dblA, xi, cw, cb, xpw, dtw, dtbp, lyr, xc, dtv, Bm, Cm);
    else       convfused_body<0>(xcs, dblA, xi, cw, cb, xpw, dtw, dtbp, lyr, xc, dtv, Bm, Cm);
}

// ---------------- chunked selective scan: 16 chunks of 64 steps (LDS-staged) ----------------
template<int BF>
__device__ void scan1_body(unsigned short* dts, unsigned short* xcs, float* Bs,
                           const unsigned short* __restrict__ dt,
                           const unsigned short* __restrict__ xc,
                           const float* __restrict__ Bm, const void* __restrict__ Alog,
                           int aoff, float* __restrict__ chA, float* __restrict__ chH)
{
    const int b = blockIdx.z, ch = blockIdx.y;
    const int tid = threadIdx.x;
    const int cl = tid >> 4;
    const int c = blockIdx.x * 16 + cl;
    const int n = tid & 15;
    const int tbase = (b << 10) + ch * 64;
    {
        const int row = tid >> 2, part = (tid & 3) * 4;
        const int c0 = blockIdx.x * 16;
        *(us4*)&dts[row * 16 + part] =
            *(const us4*)(dt + (size_t)(tbase + row) * 384 + c0 + part);
        *(us4*)&xcs[row * 16 + part] =
            *(const us4*)(xc + (size_t)(tbase + row) * 384 + c0 + part);
        *(float4*)&Bs[tid * 4] = *(const float4*)(Bm + (size_t)tbase * 16 + tid * 4);
    }
    __syncthreads();
    const float Ac = -expf(ld<BF>(Alog, (size_t)aoff + c * 16 + n));
    float h = 0.f, ap = 1.f;
#pragma unroll 4
    for (int i = 0; i < 64; i++) {
        float d = bf2f(dts[i * 16 + cl]);
        float u = bf2f(xcs[i * 16 + cl]);
        float bn = Bs[i * 16 + n];
        float dA = expf(d * Ac);
        h = fmaf(h, dA, d * u * bn);
        ap *= dA;
    }
    size_t idx = ((size_t)((b * 16 + ch) * 384 + c)) * 16 + n;
    chA[idx] = ap;
    chH[idx] = h;
}

__global__ __launch_bounds__(256)
void scan1_kernel(const int* flag, const unsigned short* dt, const unsigned short* xc,
                  const float* Bm, const void* Alog, int aoff, float* chA, float* chH)
{
    __shared__ unsigned short dts[1024];
    __shared__ unsigned short xcs[1024];
    __shared__ float Bs[1024];
    if (*flag) scan1_body<1>(dts, xcs, Bs, dt, xc, Bm, Alog, aoff, chA, chH);
    else       scan1_body<0>(dts, xcs, Bs, dt, xc, Bm, Alog, aoff, chA, chH);
}

template<int BF>
__device__ void scan2_body(unsigned short* dts, unsigned short* xcs, unsigned short* zss,
                           float* Bs, float* Cs,
                           const unsigned short* __restrict__ dt,
                           const unsigned short* __restrict__ xc,
                           const float* __restrict__ Bm, const float* __restrict__ Cm,
                           const unsigned short* __restrict__ zs,
                           const void* __restrict__ Alog, const void* __restrict__ Dp,
                           int aoff, int doff,
                           const float* __restrict__ chA, const float* __restrict__ chH,
                           unsigned short* __restrict__ y)
{
    const int b = blockIdx.z, ch = blockIdx.y;
    const int tid = threadIdx.x;
    const int cl = tid >> 4;
    const int c = blockIdx.x * 16 + cl;
    const int n = tid & 15;
    const int tbase = (b << 10) + ch * 64;
    {
        const int row = tid >> 2, part = (tid & 3) * 4;
        const int c0 = blockIdx.x * 16;
        *(us4*)&dts[row * 16 + part] =
            *(const us4*)(dt + (size_t)(tbase + row) * 384 + c0 + part);
        *(us4*)&xcs[row * 16 + part] =
            *(const us4*)(xc + (size_t)(tbase + row) * 384 + c0 + part);
        *(us4*)&zss[row * 16 + part] =
            *(const us4*)(zs + (size_t)(tbase + row) * 384 + c0 + part);
        *(float4*)&Bs[tid * 4] = *(const float4*)(Bm + (size_t)tbase * 16 + tid * 4);
        *(float4*)&Cs[tid * 4] = *(const float4*)(Cm + (size_t)tbase * 16 + tid * 4);
    }
    const float Ac = -expf(ld<BF>(Alog, (size_t)aoff + c * 16 + n));
    const float dp = ld<BF>(Dp, (size_t)doff + c);
    float h = 0.f;
    for (int c2 = 0; c2 < ch; c2++) {
        size_t i2 = ((size_t)((b * 16 + c2) * 384 + c)) * 16 + n;
        h = fmaf(chA[i2], h, chH[i2]);
    }
    __syncthreads();
#pragma unroll 4
    for (int i = 0; i < 64; i++) {
        float d = bf2f(dts[i * 16 + cl]);
        float u = bf2f(xcs[i * 16 + cl]);
        float bn = Bs[i * 16 + n];
        float cn = Cs[i * 16 + n];
        float dA = expf(d * Ac);
        h = fmaf(h, dA, d * u * bn);
        float p = h * cn;
        p += __shfl_xor(p, 1);
        p += __shfl_xor(p, 2);
        p += __shfl_xor(p, 4);
        p += __shfl_xor(p, 8);
        if (n == 0) {
            int t = tbase + i;
            y[(size_t)t * 384 + c] = f2bf((p + u * dp) * bf2f(zss[i * 16 + cl]));
        }
    }
}

__global__ __launch_bounds__(256)
void scan2_kernel(const int* flag, const unsigned short* dt, const unsigned short* xc,
                  const float* Bm, const float* Cm, const unsigned short* zs,
                  const void* Alog, const void* Dp, int aoff, int doff,
                  const float* chA, const float* chH, unsigned short* y)
{
    __shared__ unsigned short dts[1024];
    __shared__ unsigned short xcs[1024];
    __shared__ unsigned short zss[1024];
    __shared__ float Bs[1024];
    __shared__ float Cs[1024];
    if (*flag) scan2_body<1>(dts, xcs, zss, Bs, Cs, dt, xc, Bm, Cm, zs, Alog, Dp,
                             aoff, doff, chA, chH, y);
    else       scan2_body<0>(dts, xcs, zss, Bs, Cs, dt, xc, Bm, Cm, zs, Alog, Dp,
                             aoff, doff, chA, chH, y);
}

extern "C" void kernel_launch(void* const* d_in, const int* in_sizes, int n_in,
                              void* d_out, int out_size, void* d_ws, size_t ws_size,
                              hipStream_t stream) {
    const void* x        = d_in[0];
    const void* bparams  = d_in[1];
    const void* patch_w  = d_in[2];
    const void* patch_b  = d_in[3];
    const void* in_proj  = d_in[4];
    const void* conv_w   = d_in[5];
    const void* conv_b   = d_in[6];
    const void* x_proj   = d_in[7];
    const void* dt_w     = d_in[8];
    const void* dt_b     = d_in[9];
    const void* A_log    = d_in[10];
    const void* Dskip    = d_in[11];
    const void* out_proj = d_in[12];
    const void* norm_w   = d_in[13];
    const void* norm_b   = d_in[14];
    const void* fnw      = d_in[15];
    const void* fnb      = d_in[16];
    const unsigned char* maskp = (const unsigned char*)d_in[17];

    const size_t TD = (size_t)NTOK * 384;        // 786432 elements
    char* p = (char*)d_ws;
    float* tok = (float*)p;              p += TD * 4;          // f32 residual stream
    unsigned short* hbuf = (unsigned short*)p; p += TD * 2;    // yb (scan2 out)
    unsigned short* xi   = (unsigned short*)p; p += TD * 2;
    unsigned short* zs   = (unsigned short*)p; p += TD * 2;
    unsigned short* xc   = (unsigned short*)p; p += TD * 2;
    unsigned short* dtb_ = (unsigned short*)p; p += TD * 2;
    float* Bmb = (float*)p;              p += (size_t)NTOK * 16 * 4;
    float* Cmb = (float*)p;              p += (size_t)NTOK * 16 * 4;
    float* chA = (float*)p;              p += 196608 * 4;
    float* chH = (float*)p;              p += 196608 * 4;
    int* dflag = (int*)p;                p += 256;
    unsigned short* wbase = (unsigned short*)p;
    const size_t fixed = (size_t)(p - (char*)d_ws);
    const int big = (ws_size >= fixed + (size_t)(12 * 294912 + 12 * 147456) * 2 + 4096);

    unsigned short* wtP   = wbase;
    unsigned short* wtL12 = wbase;
    unsigned short* wtO12 = wbase + (size_t)12 * 294912;
    unsigned short* wtLs  = wbase + (size_t)1572864;
    unsigned short* wtOs  = wtLs + (size_t)294912;
    unsigned short* yb    = hbuf;

    detect_kernel<<<1, 1, 0, stream>>>(Dskip, dflag);
    transposeP_kernel<<<1536, 256, 0, stream>>>(dflag, patch_w, wtP);
    posinit_kernel<<<3072, 256, 0, stream>>>(dflag, patch_b, bparams, maskp, tok);
    patch_kernel<<<dim3(32, 6, 4), 256, 0, stream>>>(dflag, x, wtP, tok);
    if (big)
        transposeAll_kernel<<<dim3(432, 12), 256, 0, stream>>>(dflag, in_proj, out_proj,
                                                               wtL12, wtO12);

    for (int lyr = 0; lyr < 12; lyr++) {
        unsigned short *wtL, *wtO;
        if (big) {
            wtL = wtL12 + (size_t)lyr * 294912;
            wtO = wtO12 + (size_t)lyr * 147456;
        } else {
            transposeL_kernel<<<432, 256, 0, stream>>>(dflag, in_proj, out_proj, lyr,
                                                       wtLs, wtOs);
            wtL = wtLs; wtO = wtOs;
        }
        lngemm_kernel<<<dim3(64, 12), 256, 0, stream>>>(
            dflag, tok, norm_w, norm_b, lyr * 384, wtL, xi, zs);
        convfused_kernel<<<NTOK / 4, 256, 0, stream>>>(
            dflag, xi, conv_w, conv_b, x_proj, dt_w, dt_b, lyr, xc, dtb_, Bmb, Cmb);
        scan1_kernel<<<dim3(24, 16, 2), 256, 0, stream>>>(
            dflag, dtb_, xc, Bmb, A_log, lyr * 384 * 16, chA, chH);
        scan2_kernel<<<dim3(24, 16, 2), 256, 0, stream>>>(
            dflag, dtb_, xc, Bmb, Cmb, zs, A_log, Dskip, lyr * 384 * 16, lyr * 384,
            chA, chH, yb);
        gemm1_kernel<<<dim3(32, 6, 2), 256, 0, stream>>>(yb, wtO, tok);
    }

    ln_kernel<<<NTOK, 64, 0, stream>>>(dflag, tok, fnw, fnb, 0, d_out, 0);
}

// Round 13
// 1233.917 us; speedup vs baseline: 1.0593x; 1.0593x over previous
//
#include <hip/hip_runtime.h>

// VisionMamba: B=2, L=1024 (16x8x8), d=384, 12 layers, dstate=16, dconv=4, dtrank=24
// R13: best-measured composition. patch = R11 (coalesced linear stage, 41us);
// gemm0/gemm1 = R10 64x64 shapes (R11 32-row split cost +6us); ln separate
// (R7+R12: LN->GEMM fusion definitively negative - prologue x12 n-tiles) but
// now 4 waves/block (wave per token, grid 512) vs 2048 1-wave blocks.
// Proven: patch z=4 4-plane, LDS-staged scans, convfused.

#define NTOK 2048

typedef short bf16x8 __attribute__((ext_vector_type(8)));
typedef float f32x4 __attribute__((ext_vector_type(4)));
typedef unsigned short us4 __attribute__((ext_vector_type(4)));

__device__ __forceinline__ float bf2f(unsigned short u) {
    return __uint_as_float(((unsigned)u) << 16);
}
__device__ __forceinline__ unsigned short f2bf(float f) {
    unsigned u = __float_as_uint(f);
    u += 0x7fffu + ((u >> 16) & 1u);
    return (unsigned short)(u >> 16);
}
__device__ __forceinline__ float siluf(float x) { return x / (1.f + expf(-x)); }

__device__ __forceinline__ float ldr(const void* p, size_t i, int bf) {
    if (bf) return bf2f(((const unsigned short*)p)[i]);
    return ((const float*)p)[i];
}
template<int BF>
__device__ __forceinline__ float ld(const void* p, size_t i) {
    if (BF) return bf2f(((const unsigned short*)p)[i]);
    return ((const float*)p)[i];
}

__global__ void detect_kernel(const void* dskip, int* flag) {
    flag[0] = (((const unsigned short*)dskip)[0] == 0x3F80u) ? 1 : 0;
}

// ---------------- patch_w transpose: [4096][384] -> wtP[384][4096] bf16 ----------------
__global__ __launch_bounds__(256)
void transposeP_kernel(const int* flag, const void* pw, unsigned short* wtP)
{
    __shared__ unsigned short Ts[32 * 36];
    const int bid = blockIdx.x;           // 1536 = 128 kb x 12 nb
    const int kb = bid / 12, nb = bid % 12;
    const int tid = threadIdx.x;
    const int r = tid >> 3, c0 = (tid & 7) * 4;
    const int BF = *flag;
#pragma unroll
    for (int i = 0; i < 4; i++) {
        size_t si = (size_t)(kb * 32 + r) * 384 + nb * 32 + c0 + i;
        Ts[(c0 + i) * 36 + r] = f2bf(ldr(pw, si, BF));
    }
    __syncthreads();
    *(us4*)(wtP + (size_t)(nb * 32 + r) * 4096 + kb * 32 + c0) = *(const us4*)&Ts[r * 36 + c0];
}

// ---------- per-layer transpose (small-ws fallback): in_proj->wtL, out_proj->wtO ----------
__global__ __launch_bounds__(256)
void transposeL_kernel(const int* flag, const void* ipw, const void* opw, int lyr,
                       unsigned short* wtL, unsigned short* wtOl)
{
    __shared__ unsigned short Ts[32 * 36];
    const int bid = blockIdx.x;           // 432 = 288 (in_proj 12kb x 24nb) + 144 (12x12)
    const void* src; size_t soff; unsigned short* dst; int N, kb, nb;
    if (bid < 288) {
        src = ipw; soff = (size_t)lyr * 294912; dst = wtL; N = 768;
        kb = bid / 24; nb = bid % 24;
    } else {
        int rel = bid - 288;
        src = opw; soff = (size_t)lyr * 147456; dst = wtOl; N = 384;
        kb = rel / 12; nb = rel % 12;
    }
    const int tid = threadIdx.x;
    const int r = tid >> 3, c0 = (tid & 7) * 4;
    const int BF = *flag;
#pragma unroll
    for (int i = 0; i < 4; i++) {
        size_t si = soff + (size_t)(kb * 32 + r) * N + nb * 32 + c0 + i;
        Ts[(c0 + i) * 36 + r] = f2bf(ldr(src, si, BF));
    }
    __syncthreads();
    *(us4*)(dst + (size_t)(nb * 32 + r) * 384 + kb * 32 + c0) = *(const us4*)&Ts[r * 36 + c0];
}

// ---------- all-layer transpose (big-ws mode): one dispatch for 12 layers ----------
__global__ __launch_bounds__(256)
void transposeAll_kernel(const int* flag, const void* ipw, const void* opw,
                         unsigned short* wtL12, unsigned short* wtO12)
{
    __shared__ unsigned short Ts[32 * 36];
    const int lyr = blockIdx.y;
    const int bid = blockIdx.x;           // 432 per layer
    const void* src; size_t soff; unsigned short* dst; int N, kb, nb;
    if (bid < 288) {
        src = ipw; soff = (size_t)lyr * 294912;
        dst = wtL12 + (size_t)lyr * 294912; N = 768;
        kb = bid / 24; nb = bid % 24;
    } else {
        int rel = bid - 288;
        src = opw; soff = (size_t)lyr * 147456;
        dst = wtO12 + (size_t)lyr * 147456; N = 384;
        kb = rel / 12; nb = rel % 12;
    }
    const int tid = threadIdx.x;
    const int r = tid >> 3, c0 = (tid & 7) * 4;
    const int BF = *flag;
#pragma unroll
    for (int i = 0; i < 4; i++) {
        size_t si = soff + (size_t)(kb * 32 + r) * N + nb * 32 + c0 + i;
        Ts[(c0 + i) * 36 + r] = f2bf(ldr(src, si, BF));
    }
    __syncthreads();
    *(us4*)(dst + (size_t)(nb * 32 + r) * 384 + kb * 32 + c0) = *(const us4*)&Ts[r * 36 + c0];
}

// ================= MFMA GEMMs (R10 shapes) =================
// block 256 = 4 waves; block tile 64m x 64n; wave (w&1,w>>1) -> 32x32; 2x2 16x16x32 frags.
template<int MODE>  // 0: in_proj -> xi | silu(z);  1: out_proj K-split z=2 -> tok atomicAdd
__global__ __launch_bounds__(256)
void gemm_kernel(const unsigned short* __restrict__ A,
                 const unsigned short* __restrict__ WT,
                 void* __restrict__ out0, unsigned short* __restrict__ out1)
{
    const int mtile = blockIdx.x;
    const int ntile = blockIdx.y;
    const int tid = threadIdx.x;
    const int w = tid >> 6, lane = tid & 63;
    const int l15 = lane & 15, quad = lane >> 4;
    const int mbase = mtile * 64 + (w & 1) * 32;
    const int nbase = ntile * 64 + (w >> 1) * 32;
    f32x4 acc00 = {0.f,0.f,0.f,0.f}, acc01 = acc00, acc10 = acc00, acc11 = acc00;
    const bf16x8* Ap0 = (const bf16x8*)(A + (size_t)(mbase + l15) * 384 + quad * 8);
    const bf16x8* Ap1 = (const bf16x8*)(A + (size_t)(mbase + 16 + l15) * 384 + quad * 8);
    const bf16x8* Bp0 = (const bf16x8*)(WT + (size_t)(nbase + l15) * 384 + quad * 8);
    const bf16x8* Bp1 = (const bf16x8*)(WT + (size_t)(nbase + 16 + l15) * 384 + quad * 8);
    const int nkt = (MODE == 1) ? 6 : 12;
    const int kt0 = (MODE == 1) ? blockIdx.z * 6 : 0;
#pragma unroll
    for (int ki = 0; ki < nkt; ki++) {
        const int kt = kt0 + ki;
        bf16x8 a0 = Ap0[kt * 4];
        bf16x8 a1 = Ap1[kt * 4];
        bf16x8 b0 = Bp0[kt * 4];
        bf16x8 b1 = Bp1[kt * 4];
        acc00 = __builtin_amdgcn_mfma_f32_16x16x32_bf16(a0, b0, acc00, 0, 0, 0);
        acc01 = __builtin_amdgcn_mfma_f32_16x16x32_bf16(a0, b1, acc01, 0, 0, 0);
        acc10 = __builtin_amdgcn_mfma_f32_16x16x32_bf16(a1, b0, acc10, 0, 0, 0);
        acc11 = __builtin_amdgcn_mfma_f32_16x16x32_bf16(a1, b1, acc11, 0, 0, 0);
    }
    f32x4 accs[2][2] = {{acc00, acc01}, {acc10, acc11}};
#pragma unroll
    for (int mi = 0; mi < 2; mi++)
#pragma unroll
    for (int ni = 0; ni < 2; ni++)
#pragma unroll
    for (int r = 0; r < 4; r++) {
        int m = mbase + mi * 16 + quad * 4 + r;
        int n = nbase + ni * 16 + l15;
        float v = accs[mi][ni][r];
        if (MODE == 0) {
            if (n < 384) ((unsigned short*)out0)[(size_t)m * 384 + n] = f2bf(v);
            else out1[(size_t)m * 384 + (n - 384)] = f2bf(siluf(v));
        } else {
            atomicAdd(&((float*)out0)[(size_t)m * 384 + n], v);
        }
    }
}

// ---------------- pos-embed + patch_b init of tok ----------------
template<int BF>
__device__ void posinit_body(const void* __restrict__ pb, const void* __restrict__ bparams,
                             const unsigned char* __restrict__ maskp, float* __restrict__ tok)
{
    const int gid = blockIdx.x * 256 + threadIdx.x;   // 786432 total
    const int t = gid / 384;
    const int n = gid - t * 384;
    const int b = t >> 10, l = t & 1023;
    const int gh = l >> 6, gw = (l >> 3) & 7, gd = l & 7;
    const int j = n >> 7;
    const int ii = n & 127;
    const int i0 = (ii < 64) ? ii : ii - 64;
    const float omega = exp2f(-(float)i0 * 0.20762050593046014f);  // 10000^(-i/64)
    float rr = ld<BF>(bparams, b * 4 + 0);
    float ar = ld<BF>(bparams, b * 4 + 1);
    float vr = ld<BF>(bparams, b * 4 + 2);
    bool mk = maskp[b] != 0;
    float cj;
    if (j == 0) {
        float dmax = (rr >= 0.f) ? 15.f * rr : 0.f;
        if (dmax == 0.f) dmax = 1.f;
        cj = (float)gh * rr / dmax;
    } else if (j == 1) {
        float amax = 4.f * fabsf(ar);
        if (amax == 0.f) amax = 1.f;
        cj = (float)(gw - 4) * ar / amax;
    } else {
        if (mk) {
            float dmx = 4.f * fabsf(vr);
            if (dmx == 0.f) dmx = 1.f;
            cj = (float)(gd - 4) * vr / dmx;
        } else {
            float dmx = (vr >= 0.f) ? 7.f * vr : 0.f;
            if (dmx == 0.f) dmx = 1.f;
            cj = (float)gd * vr / dmx;
        }
    }
    float s = cj * omega;
    float pos = (ii < 64) ? sinf(s) : cosf(s);
    tok[gid] = ld<BF>(pb, n) + pos;
}

__global__ __launch_bounds__(256)
void posinit_kernel(const int* flag, const void* pb, const void* bparams,
                    const unsigned char* maskp, float* tok)
{
    if (*flag) posinit_body<1>(pb, bparams, maskp, tok);
    else       posinit_body<0>(pb, bparams, maskp, tok);
}

// patch MFMA with LDS-staged A: block = 64 tok x 64 n; kz covers 4 ph planes (z=4).
// Coalesced linear stage (R11): decode (gw,pw,gd,pd) from e, write As[(gw*8+gd)*260+pw*8+pd].
template<int BF>
__device__ void patch_body(const void* __restrict__ x,
                           const unsigned short* __restrict__ WT,
                           float* __restrict__ tok, short* __restrict__ As)
{
    const int mtile = blockIdx.x;   // 32  (fixed b = mtile>>4, gh = mtile&15)
    const int ntile = blockIdx.y;   // 6
    const int kz = blockIdx.z;      // 4 (each = 4 ph planes)
    const int tid = threadIdx.x;
    const int w = tid >> 6, lane = tid & 63;
    const int l15 = lane & 15, quad = lane >> 4;
    const int nbase = ntile * 64 + (w >> 1) * 32;
    const int mrow0 = (w & 1) * 32 + l15;
    const int bb0 = mtile >> 4, gh0 = mtile & 15;
    f32x4 acc00 = {0.f,0.f,0.f,0.f}, acc01 = acc00, acc10 = acc00, acc11 = acc00;
#pragma unroll
    for (int p2 = 0; p2 < 4; p2++) {
        const int plane = kz * 4 + p2;
        if (p2) __syncthreads();     // all waves done reading As before restage
        {
            const size_t sbase = (size_t)bb0 * 4194304u + (size_t)gh0 * 262144u
                               + (size_t)plane * 16384u;
#pragma unroll
            for (int it = 0; it < 16; it++) {
                int e = it * 1024 + tid * 4;
                int gw = e >> 11, pw = (e >> 6) & 31, gd = (e >> 3) & 7, pd = e & 7;
                short* dst = As + (gw * 8 + gd) * 260 + pw * 8 + pd;
                if (BF) {
                    *(us4*)dst = *(const us4*)((const unsigned short*)x + sbase + e);
                } else {
                    float4 p4 = *(const float4*)((const float*)x + sbase + e);
                    dst[0] = (short)f2bf(p4.x); dst[1] = (short)f2bf(p4.y);
                    dst[2] = (short)f2bf(p4.z); dst[3] = (short)f2bf(p4.w);
                }
            }
        }
        __syncthreads();
        const bf16x8* Bp0 = (const bf16x8*)(WT + (size_t)(nbase + l15) * 4096
                                            + plane * 256 + quad * 8);
        const bf16x8* Bp1 = (const bf16x8*)(WT + (size_t)(nbase + 16 + l15) * 4096
                                            + plane * 256 + quad * 8);
#pragma unroll
        for (int kt = 0; kt < 8; kt++) {
            const short* a0p = As + mrow0 * 260 + kt * 32 + quad * 8;
            const short* a1p = a0p + 16 * 260;
            bf16x8 a0, a1;
            {
                us4 lo = *(const us4*)a0p, hi = *(const us4*)(a0p + 4);
                a0[0]=lo[0]; a0[1]=lo[1]; a0[2]=lo[2]; a0[3]=lo[3];
                a0[4]=hi[0]; a0[5]=hi[1]; a0[6]=hi[2]; a0[7]=hi[3];
                us4 lo1 = *(const us4*)a1p, hi1 = *(const us4*)(a1p + 4);
                a1[0]=lo1[0]; a1[1]=lo1[1]; a1[2]=lo1[2]; a1[3]=lo1[3];
                a1[4]=hi1[0]; a1[5]=hi1[1]; a1[6]=hi1[2]; a1[7]=hi1[3];
            }
            bf16x8 b0 = Bp0[kt * 4];
            bf16x8 b1 = Bp1[kt * 4];
            acc00 = __builtin_amdgcn_mfma_f32_16x16x32_bf16(a0, b0, acc00, 0, 0, 0);
            acc01 = __builtin_amdgcn_mfma_f32_16x16x32_bf16(a0, b1, acc01, 0, 0, 0);
            acc10 = __builtin_amdgcn_mfma_f32_16x16x32_bf16(a1, b0, acc10, 0, 0, 0);
            acc11 = __builtin_amdgcn_mfma_f32_16x16x32_bf16(a1, b1, acc11, 0, 0, 0);
        }
    }
    f32x4 accs[2][2] = {{acc00, acc01}, {acc10, acc11}};
#pragma unroll
    for (int mi = 0; mi < 2; mi++)
#pragma unroll
    for (int ni = 0; ni < 2; ni++) {
        int n = nbase + ni * 16 + l15;
#pragma unroll
        for (int r = 0; r < 4; r++) {
            int m = mtile * 64 + (w & 1) * 32 + mi * 16 + quad * 4 + r;
            atomicAdd(&tok[(size_t)m * 384 + n], accs[mi][ni][r]);
        }
    }
}

__global__ __launch_bounds__(256)
void patch_kernel(const int* flag, const void* x, const unsigned short* wtP, float* tok)
{
    __shared__ short As[64 * 260];   // 33.3 KB
    if (*flag) patch_body<1>(x, wtP, tok, As);
    else       patch_body<0>(x, wtP, tok, As);
}

// ---------------- layernorm: 4 waves/block, wave per token (grid 512) ----------------
// obf=1: write bf16 (intermediate). obf=0: final, dtype follows flag.
__global__ __launch_bounds__(256)
void ln_kernel(const int* flag, const float* __restrict__ in, const void* __restrict__ w,
               const void* __restrict__ b, int woff, void* __restrict__ out, int obf)
{
    const int BF = *flag;
    const int wbf = obf | BF;
    const int t = blockIdx.x * 4 + (threadIdx.x >> 6);
    const int lane = threadIdx.x & 63;
    float v[6];
    float s = 0.f;
#pragma unroll
    for (int i = 0; i < 6; i++) { v[i] = in[(size_t)t * 384 + lane + 64 * i]; s += v[i]; }
#pragma unroll
    for (int o = 1; o < 64; o <<= 1) s += __shfl_xor(s, o);
    const float mu = s * (1.f / 384.f);
    float s2 = 0.f;
#pragma unroll
    for (int i = 0; i < 6; i++) { float d = v[i] - mu; s2 += d * d; }
#pragma unroll
    for (int o = 1; o < 64; o <<= 1) s2 += __shfl_xor(s2, o);
    const float rstd = rsqrtf(s2 * (1.f / 384.f) + 1e-5f);
#pragma unroll
    for (int i = 0; i < 6; i++) {
        int c = lane + 64 * i;
        float o = (v[i] - mu) * rstd * ldr(w, woff + c, BF) + ldr(b, woff + c, BF);
        if (wbf) ((unsigned short*)out)[(size_t)t * 384 + c] = f2bf(o);
        else     ((float*)out)[(size_t)t * 384 + c] = o;
    }
}

// ------- fused: causal depthwise conv(4)+silu -> x_proj (384->56) -> dt_proj (24->384) -------
template<int BF>
__device__ void convfused_body(float* xcs, float* dblA,
                          const unsigned short* __restrict__ xi,
                          const void* __restrict__ cw, const void* __restrict__ cb,
                          const void* __restrict__ xpw, const void* __restrict__ dtw,
                          const void* __restrict__ dtbp, int lyr,
                          unsigned short* __restrict__ xc, unsigned short* __restrict__ dtv,
                          float* __restrict__ Bm, float* __restrict__ Cm)
{
    const int tb = blockIdx.x * 4;
    const int tid = threadIdx.x;
    const size_t cwo = (size_t)lyr * 1536;
    const size_t cbo = (size_t)lyr * 384;
    const size_t xpo = (size_t)lyr * 21504;
    const size_t dto = (size_t)lyr * 9216;
#pragma unroll
    for (int i = 0; i < 6; i++) {
        int p = i * 256 + tid;
        int tl = p / 384, c = p - tl * 384;
        int t = tb + tl;
        int b = t >> 10, l = t & 1023;
        float acc = ld<BF>(cb, cbo + c);
#pragma unroll
        for (int jj = 0; jj < 4; jj++) {
            int ls = l - 3 + jj;
            if (ls >= 0)
                acc = fmaf(bf2f(xi[(size_t)((b << 10) + ls) * 384 + c]),
                           ld<BF>(cw, cwo + c * 4 + jj), acc);
        }
        float s = siluf(acc);
        xcs[tl * 384 + c] = s;
        xc[(size_t)t * 384 + c] = f2bf(s);
    }
    __syncthreads();
    {
        const int tok = tid >> 6, og = tid & 63;
        const int t = tb + tok;
        if (og < 56) {
            float acc = 0.f;
            const float* xr = xcs + tok * 384;
#pragma unroll 8
            for (int k = 0; k < 384; k++)
                acc = fmaf(xr[k], ld<BF>(xpw, xpo + (size_t)k * 56 + og), acc);
            if (og < 24) dblA[tok * 24 + og] = acc;
            else if (og < 40) Bm[(size_t)t * 16 + (og - 24)] = acc;
            else Cm[(size_t)t * 16 + (og - 40)] = acc;
        }
    }
    __syncthreads();
#pragma unroll
    for (int i = 0; i < 6; i++) {
        int p = i * 256 + tid;
        int tl = p / 384, c = p - tl * 384;
        int t = tb + tl;
        float acc = ld<BF>(dtbp, cbo + c);
        const float* dr = dblA + tl * 24;
#pragma unroll
        for (int r = 0; r < 24; r++)
            acc = fmaf(dr[r], ld<BF>(dtw, dto + (size_t)r * 384 + c), acc);
        float sp = fmaxf(acc, 0.f) + log1pf(expf(-fabsf(acc)));  // softplus
        dtv[(size_t)t * 384 + c] = f2bf(sp);
    }
}

__global__ __launch_bounds__(256)
void convfused_kernel(const int* flag, const unsigned short* xi, const void* cw,
                      const void* cb, const void* xpw, const void* dtw, const void* dtbp,
                      int lyr, unsigned short* xc, unsigned short* dtv,
                      float* Bm, float* Cm)
{
    __shared__ float xcs[4 * 384];
    __shared__ float dblA[4 * 24];
    if (*flag) convfused_body<1>(xcs, dblA, xi, cw, cb, xpw, dtw, dtbp, lyr, xc, dtv, Bm, Cm);
    else       convfused_body<0>(xcs, dblA, xi, cw, cb, xpw, dtw, dtbp, lyr, xc, dtv, Bm, Cm);
}

// ---------------- chunked selective scan: 16 chunks of 64 steps (LDS-staged) ----------------
template<int BF>
__device__ void scan1_body(unsigned short* dts, unsigned short* xcs, float* Bs,
                           const unsigned short* __restrict__ dt,
                           const unsigned short* __restrict__ xc,
                           const float* __restrict__ Bm, const void* __restrict__ Alog,
                           int aoff, float* __restrict__ chA, float* __restrict__ chH)
{
    const int b = blockIdx.z, ch = blockIdx.y;
    const int tid = threadIdx.x;
    const int cl = tid >> 4;
    const int c = blockIdx.x * 16 + cl;
    const int n = tid & 15;
    const int tbase = (b << 10) + ch * 64;
    {
        const int row = tid >> 2, part = (tid & 3) * 4;
        const int c0 = blockIdx.x * 16;
        *(us4*)&dts[row * 16 + part] =
            *(const us4*)(dt + (size_t)(tbase + row) * 384 + c0 + part);
        *(us4*)&xcs[row * 16 + part] =
            *(const us4*)(xc + (size_t)(tbase + row) * 384 + c0 + part);
        *(float4*)&Bs[tid * 4] = *(const float4*)(Bm + (size_t)tbase * 16 + tid * 4);
    }
    __syncthreads();
    const float Ac = -expf(ld<BF>(Alog, (size_t)aoff + c * 16 + n));
    float h = 0.f, ap = 1.f;
#pragma unroll 4
    for (int i = 0; i < 64; i++) {
        float d = bf2f(dts[i * 16 + cl]);
        float u = bf2f(xcs[i * 16 + cl]);
        float bn = Bs[i * 16 + n];
        float dA = expf(d * Ac);
        h = fmaf(h, dA, d * u * bn);
        ap *= dA;
    }
    size_t idx = ((size_t)((b * 16 + ch) * 384 + c)) * 16 + n;
    chA[idx] = ap;
    chH[idx] = h;
}

__global__ __launch_bounds__(256)
void scan1_kernel(const int* flag, const unsigned short* dt, const unsigned short* xc,
                  const float* Bm, const void* Alog, int aoff, float* chA, float* chH)
{
    __shared__ unsigned short dts[1024];
    __shared__ unsigned short xcs[1024];
    __shared__ float Bs[1024];
    if (*flag) scan1_body<1>(dts, xcs, Bs, dt, xc, Bm, Alog, aoff, chA, chH);
    else       scan1_body<0>(dts, xcs, Bs, dt, xc, Bm, Alog, aoff, chA, chH);
}

template<int BF>
__device__ void scan2_body(unsigned short* dts, unsigned short* xcs, unsigned short* zss,
                           float* Bs, float* Cs,
                           const unsigned short* __restrict__ dt,
                           const unsigned short* __restrict__ xc,
                           const float* __restrict__ Bm, const float* __restrict__ Cm,
                           const unsigned short* __restrict__ zs,
                           const void* __restrict__ Alog, const void* __restrict__ Dp,
                           int aoff, int doff,
                           const float* __restrict__ chA, const float* __restrict__ chH,
                           unsigned short* __restrict__ y)
{
    const int b = blockIdx.z, ch = blockIdx.y;
    const int tid = threadIdx.x;
    const int cl = tid >> 4;
    const int c = blockIdx.x * 16 + cl;
    const int n = tid & 15;
    const int tbase = (b << 10) + ch * 64;
    {
        const int row = tid >> 2, part = (tid & 3) * 4;
        const int c0 = blockIdx.x * 16;
        *(us4*)&dts[row * 16 + part] =
            *(const us4*)(dt + (size_t)(tbase + row) * 384 + c0 + part);
        *(us4*)&xcs[row * 16 + part] =
            *(const us4*)(xc + (size_t)(tbase + row) * 384 + c0 + part);
        *(us4*)&zss[row * 16 + part] =
            *(const us4*)(zs + (size_t)(tbase + row) * 384 + c0 + part);
        *(float4*)&Bs[tid * 4] = *(const float4*)(Bm + (size_t)tbase * 16 + tid * 4);
        *(float4*)&Cs[tid * 4] = *(const float4*)(Cm + (size_t)tbase * 16 + tid * 4);
    }
    const float Ac = -expf(ld<BF>(Alog, (size_t)aoff + c * 16 + n));
    const float dp = ld<BF>(Dp, (size_t)doff + c);
    float h = 0.f;
    for (int c2 = 0; c2 < ch; c2++) {
        size_t i2 = ((size_t)((b * 16 + c2) * 384 + c)) * 16 + n;
        h = fmaf(chA[i2], h, chH[i2]);
    }
    __syncthreads();
#pragma unroll 4
    for (int i = 0; i < 64; i++) {
        float d = bf2f(dts[i * 16 + cl]);
        float u = bf2f(xcs[i * 16 + cl]);
        float bn = Bs[i * 16 + n];
        float cn = Cs[i * 16 + n];
        float dA = expf(d * Ac);
        h = fmaf(h, dA, d * u * bn);
        float p = h * cn;
        p += __shfl_xor(p, 1);
        p += __shfl_xor(p, 2);
        p += __shfl_xor(p, 4);
        p += __shfl_xor(p, 8);
        if (n == 0) {
            int t = tbase + i;
            y[(size_t)t * 384 + c] = f2bf((p + u * dp) * bf2f(zss[i * 16 + cl]));
        }
    }
}

__global__ __launch_bounds__(256)
void scan2_kernel(const int* flag, const unsigned short* dt, const unsigned short* xc,
                  const float* Bm, const float* Cm, const unsigned short* zs,
                  const void* Alog, const void* Dp, int aoff, int doff,
                  const float* chA, const float* chH, unsigned short* y)
{
    __shared__ unsigned short dts[1024];
    __shared__ unsigned short xcs[1024];
    __shared__ unsigned short zss[1024];
    __shared__ float Bs[1024];
    __shared__ float Cs[1024];
    if (*flag) scan2_body<1>(dts, xcs, zss, Bs, Cs, dt, xc, Bm, Cm, zs, Alog, Dp,
                             aoff, doff, chA, chH, y);
    else       scan2_body<0>(dts, xcs, zss, Bs, Cs, dt, xc, Bm, Cm, zs, Alog, Dp,
                             aoff, doff, chA, chH, y);
}

extern "C" void kernel_launch(void* const* d_in, const int* in_sizes, int n_in,
                              void* d_out, int out_size, void* d_ws, size_t ws_size,
                              hipStream_t stream) {
    const void* x        = d_in[0];
    const void* bparams  = d_in[1];
    const void* patch_w  = d_in[2];
    const void* patch_b  = d_in[3];
    const void* in_proj  = d_in[4];
    const void* conv_w   = d_in[5];
    const void* conv_b   = d_in[6];
    const void* x_proj   = d_in[7];
    const void* dt_w     = d_in[8];
    const void* dt_b     = d_in[9];
    const void* A_log    = d_in[10];
    const void* Dskip    = d_in[11];
    const void* out_proj = d_in[12];
    const void* norm_w   = d_in[13];
    const void* norm_b   = d_in[14];
    const void* fnw      = d_in[15];
    const void* fnb      = d_in[16];
    const unsigned char* maskp = (const unsigned char*)d_in[17];

    const size_t TD = (size_t)NTOK * 384;        // 786432 elements
    char* p = (char*)d_ws;
    float* tok = (float*)p;              p += TD * 4;          // f32 residual stream
    unsigned short* hbuf = (unsigned short*)p; p += TD * 2;    // ln out; reused as yb
    unsigned short* xi   = (unsigned short*)p; p += TD * 2;
    unsigned short* zs   = (unsigned short*)p; p += TD * 2;
    unsigned short* xc   = (unsigned short*)p; p += TD * 2;
    unsigned short* dtb_ = (unsigned short*)p; p += TD * 2;
    float* Bmb = (float*)p;              p += (size_t)NTOK * 16 * 4;
    float* Cmb = (float*)p;              p += (size_t)NTOK * 16 * 4;
    float* chA = (float*)p;              p += 196608 * 4;
    float* chH = (float*)p;              p += 196608 * 4;
    int* dflag = (int*)p;                p += 256;
    unsigned short* wbase = (unsigned short*)p;
    const size_t fixed = (size_t)(p - (char*)d_ws);
    const int big = (ws_size >= fixed + (size_t)(12 * 294912 + 12 * 147456) * 2 + 4096);

    unsigned short* wtP   = wbase;
    unsigned short* wtL12 = wbase;
    unsigned short* wtO12 = wbase + (size_t)12 * 294912;
    unsigned short* wtLs  = wbase + (size_t)1572864;
    unsigned short* wtOs  = wtLs + (size_t)294912;
    unsigned short* yb    = hbuf;   // scan2 output reuses ln buffer (hbuf dead by then)

    detect_kernel<<<1, 1, 0, stream>>>(Dskip, dflag);
    transposeP_kernel<<<1536, 256, 0, stream>>>(dflag, patch_w, wtP);
    posinit_kernel<<<3072, 256, 0, stream>>>(dflag, patch_b, bparams, maskp, tok);
    patch_kernel<<<dim3(32, 6, 4), 256, 0, stream>>>(dflag, x, wtP, tok);
    if (big)
        transposeAll_kernel<<<dim3(432, 12), 256, 0, stream>>>(dflag, in_proj, out_proj,
                                                               wtL12, wtO12);

    for (int lyr = 0; lyr < 12; lyr++) {
        unsigned short *wtL, *wtO;
        if (big) {
            wtL = wtL12 + (size_t)lyr * 294912;
            wtO = wtO12 + (size_t)lyr * 147456;
        } else {
            transposeL_kernel<<<432, 256, 0, stream>>>(dflag, in_proj, out_proj, lyr,
                                                       wtLs, wtOs);
            wtL = wtLs; wtO = wtOs;
        }
        ln_kernel<<<NTOK / 4, 256, 0, stream>>>(dflag, tok, norm_w, norm_b,
                                                lyr * 384, hbuf, 1);
        gemm_kernel<0><<<dim3(32, 12), 256, 0, stream>>>(hbuf, wtL, xi, zs);
        convfused_kernel<<<NTOK / 4, 256, 0, stream>>>(
            dflag, xi, conv_w, conv_b, x_proj, dt_w, dt_b, lyr, xc, dtb_, Bmb, Cmb);
        scan1_kernel<<<dim3(24, 16, 2), 256, 0, stream>>>(
            dflag, dtb_, xc, Bmb, A_log, lyr * 384 * 16, chA, chH);
        scan2_kernel<<<dim3(24, 16, 2), 256, 0, stream>>>(
            dflag, dtb_, xc, Bmb, Cmb, zs, A_log, Dskip, lyr * 384 * 16, lyr * 384,
            chA, chH, yb);
        gemm_kernel<1><<<dim3(32, 6, 2), 256, 0, stream>>>(yb, wtO, tok, nullptr);
    }

    ln_kernel<<<NTOK / 4, 256, 0, stream>>>(dflag, tok, fnw, fnb, 0, d_out, 0);
}